// Round 15
// baseline (965.807 us; speedup 1.0000x reference)
//
#include <hip/hip_runtime.h>
#include <hip/hip_bf16.h>

#define N_NODES 100000
#define NFEAT 256
#define NHID 128
#define NEDGE 3200000
#define NPAIR 200000
#define NSTEPS 5

typedef __attribute__((ext_vector_type(8))) short short8x;   // 8 bf16 (4 VGPR)
typedef __attribute__((ext_vector_type(4))) float f32x4;

__device__ __forceinline__ float sigmoidf_(float x) {
    return 1.f / (1.f + __expf(-x));
}
__device__ __forceinline__ unsigned short f2bf_bits(float f) {
    union { float f; unsigned int u; } c; c.f = f;
    unsigned int r = (c.u + 0x7FFFu + ((c.u >> 16) & 1u)) >> 16;
    return (unsigned short)r;
}
__device__ __forceinline__ float bf_bits2f(unsigned short b) {
    union { float f; unsigned int u; } c; c.u = ((unsigned int)b) << 16;
    return c.f;
}
// conflict-free LDS chunk offsets
__device__ __forceinline__ int swz8(int row, int q) {     // 32-wide rows
    return row * 32 + ((q + (row >> 1)) & 3) * 8;
}
__device__ __forceinline__ int swz64(int row, int q) {    // 64-wide rows
    return row * 64 + ((q + (row >> 1)) & 7) * 8;
}

// ---------------- utility ------------------------------------------------------
__global__ void build_row_ptr(const int* __restrict__ rows, int E, int N, int* __restrict__ row_ptr) {
    int i = blockIdx.x * blockDim.x + threadIdx.x;
    if (i > N) return;
    int lo = 0, hi = E;
    while (lo < hi) {
        int mid = (lo + hi) >> 1;
        if (rows[mid] < i) lo = mid + 1; else hi = mid;
    }
    row_ptr[i] = lo;
}

// ---------------- mega weight pack (kch = k-chunk size 32 or 64) --------------
struct PackDesc {
    const float* src;
    unsigned short* dst;
    int K, NCsrc, NCtot, coff, koff, kch;
};
struct PackDescs { PackDesc d[14]; };

__global__ void pack_all(PackDescs P) {
    const PackDesc pd = P.d[blockIdx.y];
    int idx = blockIdx.x * 256 + threadIdx.x;
    if (idx >= pd.K * pd.NCsrc) return;
    int k = idx / pd.NCsrc, j = idx - k * pd.NCsrc;
    int kg = k + pd.koff;
    pd.dst[(size_t)(kg / pd.kch) * pd.NCtot * pd.kch + (size_t)(pd.coff + j) * pd.kch + (kg % pd.kch)] =
        f2bf_bits(pd.src[idx]);
}

__global__ void pack_bin(const float* __restrict__ br, const float* __restrict__ bi,
                         const float* __restrict__ bn, float* __restrict__ bin) {
    int i = blockIdx.x * blockDim.x + threadIdx.x;
    if (i >= 384) return;
    bin[i] = (i < 128) ? br[i] : (i < 256) ? bi[i - 128] : bn[i - 256];
}

// ---------------- step 0 specialization: h1 = (1 - sig(in_i)) * tanh(in_n) ----
__global__ __launch_bounds__(256) void gru_step0(
    const unsigned short* __restrict__ IN, unsigned short* __restrict__ hbf, int M)
{
    int t = blockIdx.x * 256 + threadIdx.x;
    int row = t >> 4, ch = (t & 15) * 8;
    if (row >= M) return;
    size_t ib = (size_t)row * 384;
    short8x vi = *reinterpret_cast<const short8x*>(IN + ib + 128 + ch);
    short8x vn = *reinterpret_cast<const short8x*>(IN + ib + 256 + ch);
    short8x o;
    #pragma unroll
    for (int j = 0; j < 8; j++) {
        float ii = sigmoidf_(bf_bits2f((unsigned short)vi[j]));
        float nn = tanhf(bf_bits2f((unsigned short)vn[j]));
        o[j] = (short)f2bf_bits((1.f - ii) * nn);
    }
    *reinterpret_cast<short8x*>(hbf + (size_t)row * 128 + ch) = o;
}

// ---------------- SpMM (bf16), 4 edge streams x 4 unroll ----------------------
#define SPMM_ACC(hv, we) { \
    acc[0] += (we) * bf_bits2f((unsigned short)(hv).x); \
    acc[1] += (we) * bf_bits2f((unsigned short)((hv).x >> 16)); \
    acc[2] += (we) * bf_bits2f((unsigned short)(hv).y); \
    acc[3] += (we) * bf_bits2f((unsigned short)((hv).y >> 16)); \
    acc[4] += (we) * bf_bits2f((unsigned short)(hv).z); \
    acc[5] += (we) * bf_bits2f((unsigned short)((hv).z >> 16)); \
    acc[6] += (we) * bf_bits2f((unsigned short)(hv).w); \
    acc[7] += (we) * bf_bits2f((unsigned short)((hv).w >> 16)); }

__global__ __launch_bounds__(256) void spmm_bf16_ilp(
    const int* __restrict__ row_ptr, const int* __restrict__ col,
    const float* __restrict__ w, const unsigned short* __restrict__ hbf,
    unsigned short* __restrict__ hsbf, int N)
{
    int v = blockIdx.x * 4 + (threadIdx.x >> 6);
    int lane = threadIdx.x & 63;
    int g = lane >> 4;
    int l16 = lane & 15;
    if (v >= N) return;
    int e0 = row_ptr[v], e1 = row_ptr[v + 1];
    float acc[8] = {};
    int e = e0 + g;
    for (; e + 12 < e1; e += 16) {
        int c1 = col[e], c2 = col[e + 4], c3 = col[e + 8], c4 = col[e + 12];
        float w1 = w[e], w2 = w[e + 4], w3 = w[e + 8], w4 = w[e + 12];
        const uint4 h1 = *reinterpret_cast<const uint4*>(hbf + (size_t)c1 * NHID + l16 * 8);
        const uint4 h2 = *reinterpret_cast<const uint4*>(hbf + (size_t)c2 * NHID + l16 * 8);
        const uint4 h3 = *reinterpret_cast<const uint4*>(hbf + (size_t)c3 * NHID + l16 * 8);
        const uint4 h4 = *reinterpret_cast<const uint4*>(hbf + (size_t)c4 * NHID + l16 * 8);
        SPMM_ACC(h1, w1) SPMM_ACC(h2, w2) SPMM_ACC(h3, w3) SPMM_ACC(h4, w4)
    }
    for (; e < e1; e += 4) {
        int cc = col[e];
        float we = w[e];
        const uint4 hv = *reinterpret_cast<const uint4*>(hbf + (size_t)cc * NHID + l16 * 8);
        SPMM_ACC(hv, we)
    }
    #pragma unroll
    for (int q = 0; q < 8; q++) {
        acc[q] += __shfl_xor(acc[q], 16, 64);
        acc[q] += __shfl_xor(acc[q], 32, 64);
    }
    if (g == 0) {
        uint4 o;
        o.x = (unsigned int)f2bf_bits(acc[0]) | ((unsigned int)f2bf_bits(acc[1]) << 16);
        o.y = (unsigned int)f2bf_bits(acc[2]) | ((unsigned int)f2bf_bits(acc[3]) << 16);
        o.z = (unsigned int)f2bf_bits(acc[4]) | ((unsigned int)f2bf_bits(acc[5]) << 16);
        o.w = (unsigned int)f2bf_bits(acc[6]) | ((unsigned int)f2bf_bits(acc[7]) << 16);
        *reinterpret_cast<uint4*>(hsbf + (size_t)v * NHID + l16 * 8) = o;
    }
}

// ---------------- gate GEMM (K=256, BK=64) + GRU: BM=128, 512 threads ---------
// B fragments read DIRECTLY from WBg (196 KB, L2-resident) — no Bs staging.
// WBg packed [s(64k)][384 cols][64 k]; fragment addr = c*64 + chunk*8.
__global__ __launch_bounds__(512, 2) void gate_step_mfma(
    const unsigned short* __restrict__ hsbf, unsigned short* __restrict__ hbf,
    const unsigned short* __restrict__ IN, const unsigned short* __restrict__ WBg, int M)
{
    __shared__ unsigned short As[128 * 64];   // 16 KB (A only)

    const int tid = threadIdx.x;
    const int wid = tid >> 6;          // 0..7
    const int lane = tid & 63;
    const int row0 = blockIdx.x * 128;
    const int l15 = lane & 15;
    const int lhi = lane >> 4;

    f32x4 acc[3][8] = {};              // [panel][rowblk]

    const int ar = tid >> 2;           // 0..127
    const int aq = tid & 3;            // stages chunks aq and aq+4
    const int agr = row0 + ar;

    for (int s = 0; s < 4; s++) {
        // ---- stage A: 128 rows x 64 k ----
        {
            short8x v0 = short8x(0), v1 = short8x(0);
            if (agr < M) {
                const unsigned short* src = (s < 2)
                    ? (hbf  + (size_t)agr * 128 + s * 64)
                    : (hsbf + (size_t)agr * 128 + (s - 2) * 64);
                v0 = *reinterpret_cast<const short8x*>(src + aq * 8);
                v1 = *reinterpret_cast<const short8x*>(src + (aq + 4) * 8);
            }
            *reinterpret_cast<short8x*>(&As[swz64(ar, aq)]) = v0;
            *reinterpret_cast<short8x*>(&As[swz64(ar, aq + 4)]) = v1;
        }
        __syncthreads();

        const unsigned short* wbs = WBg + (size_t)s * 384 * 64;
        #pragma unroll
        for (int half = 0; half < 2; half++) {
            short8x a[8];
            #pragma unroll
            for (int rb = 0; rb < 8; rb++)
                a[rb] = *reinterpret_cast<const short8x*>(&As[swz64(16 * rb + l15, 4 * half + lhi)]);
            #pragma unroll
            for (int p = 0; p < 3; p++) {
                int c0 = 128 * p + 16 * wid + l15;
                short8x b = *reinterpret_cast<const short8x*>(wbs + c0 * 64 + (4 * half + lhi) * 8);
                #pragma unroll
                for (int rb = 0; rb < 8; rb++)
                    acc[p][rb] = __builtin_amdgcn_mfma_f32_16x16x32_bf16(b, a[rb], acc[p][rb], 0, 0, 0);
            }
        }
        __syncthreads();
    }

    // GRU epilogue: per lane, row = row0+16rb+l15, 4 consecutive cols at cq
    const int cq = 16 * wid + 4 * lhi;
    #pragma unroll
    for (int rb = 0; rb < 8; rb++) {
        int row = row0 + 16 * rb + l15;
        if (row >= M) continue;
        size_t ib = (size_t)row * 384;
        size_t ob = (size_t)row * 128;
        const ushort4 vr = *reinterpret_cast<const ushort4*>(IN + ib + cq);
        const ushort4 vi = *reinterpret_cast<const ushort4*>(IN + ib + 128 + cq);
        const ushort4 vn = *reinterpret_cast<const ushort4*>(IN + ib + 256 + cq);
        const ushort4 vh = *reinterpret_cast<const ushort4*>(hbf + ob + cq);
        const unsigned short ra[4] = {vr.x, vr.y, vr.z, vr.w};
        const unsigned short ia[4] = {vi.x, vi.y, vi.z, vi.w};
        const unsigned short na[4] = {vn.x, vn.y, vn.z, vn.w};
        const unsigned short ha[4] = {vh.x, vh.y, vh.z, vh.w};
        unsigned short oa[4];
        #pragma unroll
        for (int j = 0; j < 4; j++) {
            float g_r = acc[0][rb][j] + bf_bits2f(ra[j]);
            float g_i = acc[1][rb][j] + bf_bits2f(ia[j]);
            float rr = sigmoidf_(g_r);
            float gi = sigmoidf_(g_i);
            float nn = tanhf(bf_bits2f(na[j]) + rr * acc[2][rb][j]);
            oa[j] = f2bf_bits((1.f - gi) * nn + gi * bf_bits2f(ha[j]));
        }
        ushort4 st; st.x = oa[0]; st.y = oa[1]; st.z = oa[2]; st.w = oa[3];
        *reinterpret_cast<ushort4*>(hbf + ob + cq) = st;
    }
}

// ---------------- IN projection: BM=128, 512 threads, K=256, NC=384 -----------
__global__ __launch_bounds__(512, 2) void in_proj_mfma(
    const float* __restrict__ X, const unsigned short* __restrict__ WBin,
    const float* __restrict__ bin, unsigned short* __restrict__ IN, int M)
{
    __shared__ unsigned short As[128 * 32];   // 8 KB
    __shared__ unsigned short Bs[384 * 32];   // 24 KB

    const int tid = threadIdx.x;
    const int wid = tid >> 6;
    const int lane = tid & 63;
    const int row0 = blockIdx.x * 128;
    const int l15 = lane & 15;
    const int lhi = lane >> 4;

    f32x4 acc[3][8] = {};

    const int ar = tid >> 2;
    const int aq = tid & 3;
    const int agr = row0 + ar;

    for (int s = 0; s < 8; s++) {
        {
            short8x va = short8x(0);
            if (agr < M) {
                const float* src = X + (size_t)agr * 256 + s * 32 + aq * 8;
                const float4 f0 = *reinterpret_cast<const float4*>(src);
                const float4 f1 = *reinterpret_cast<const float4*>(src + 4);
                va[0] = (short)f2bf_bits(f0.x); va[1] = (short)f2bf_bits(f0.y);
                va[2] = (short)f2bf_bits(f0.z); va[3] = (short)f2bf_bits(f0.w);
                va[4] = (short)f2bf_bits(f1.x); va[5] = (short)f2bf_bits(f1.y);
                va[6] = (short)f2bf_bits(f1.z); va[7] = (short)f2bf_bits(f1.w);
            }
            *reinterpret_cast<short8x*>(&As[swz8(ar, aq)]) = va;
        }
        {
            const unsigned short* wbs = WBin + (size_t)s * 384 * 32;
            #pragma unroll
            for (int i = 0; i < 3; i++) {
                int id = tid + i * 512;
                int c = id >> 2, q = id & 3;
                short8x vb = *reinterpret_cast<const short8x*>(wbs + id * 8);
                *reinterpret_cast<short8x*>(&Bs[swz8(c, q)]) = vb;
            }
        }
        __syncthreads();

        short8x a[8];
        #pragma unroll
        for (int rb = 0; rb < 8; rb++)
            a[rb] = *reinterpret_cast<const short8x*>(&As[swz8(16 * rb + l15, lhi)]);
        #pragma unroll
        for (int p = 0; p < 3; p++) {
            int c0 = 128 * p + 16 * wid + l15;
            short8x b = *reinterpret_cast<const short8x*>(&Bs[swz8(c0, lhi)]);
            #pragma unroll
            for (int rb = 0; rb < 8; rb++)
                acc[p][rb] = __builtin_amdgcn_mfma_f32_16x16x32_bf16(b, a[rb], acc[p][rb], 0, 0, 0);
        }
        __syncthreads();
    }

    const int cq = 16 * wid + 4 * lhi;
    float bva[3][4];
    #pragma unroll
    for (int p = 0; p < 3; p++) {
        const float4 bv = *reinterpret_cast<const float4*>(bin + 128 * p + cq);
        bva[p][0] = bv.x; bva[p][1] = bv.y; bva[p][2] = bv.z; bva[p][3] = bv.w;
    }
    #pragma unroll
    for (int rb = 0; rb < 8; rb++) {
        int row = row0 + 16 * rb + l15;
        if (row >= M) continue;
        size_t ib = (size_t)row * 384;
        #pragma unroll
        for (int p = 0; p < 3; p++) {
            ushort4 st;
            st.x = f2bf_bits(acc[p][rb][0] + bva[p][0]);
            st.y = f2bf_bits(acc[p][rb][1] + bva[p][1]);
            st.z = f2bf_bits(acc[p][rb][2] + bva[p][2]);
            st.w = f2bf_bits(acc[p][rb][3] + bva[p][3]);
            *reinterpret_cast<ushort4*>(IN + ib + 128 * p + cq) = st;
        }
    }
}

// ---------------- fused tail: MLP x3 + LayerNorm + UV GEMM (BM=128, 512t) -----
#define XT_STRIDE 136
__global__ __launch_bounds__(512, 2) void mlp_tail(
    const unsigned short* __restrict__ hbf,
    const unsigned short* __restrict__ WB1, const unsigned short* __restrict__ WB2,
    const unsigned short* __restrict__ WB3, const unsigned short* __restrict__ WBd,
    const float* __restrict__ b1, const float* __restrict__ b2, const float* __restrict__ b3,
    const float* __restrict__ gamma, const float* __restrict__ beta,
    float* __restrict__ out_z, unsigned short* __restrict__ UV, int M)
{
    __shared__ unsigned short As[128 * 32];        // 8 KB
    __shared__ unsigned short Bs[256 * 32];        // 16 KB
    __shared__ unsigned short xT[128 * XT_STRIDE]; // 34.8 KB

    const int tid = threadIdx.x;
    const int wid = tid >> 6;        // 0..7
    const int lane = tid & 63;
    const int l15 = lane & 15;
    const int lhi = lane >> 4;
    const int row0 = blockIdx.x * 128;
    const int ar = tid >> 2;         // 0..127
    const int aq = tid & 3;

    // load h tile (128 rows), zero OOB
    #pragma unroll
    for (int i = 0; i < 4; i++) {
        int id = tid + i * 512;          // 0..2047
        int r = id >> 4, ch = id & 15;
        short8x v = short8x(0);
        if (row0 + r < M)
            v = *reinterpret_cast<const short8x*>(hbf + (size_t)(row0 + r) * 128 + ch * 8);
        *reinterpret_cast<short8x*>(&xT[r * XT_STRIDE + ch * 8]) = v;
    }
    __syncthreads();

    // 3 MLP layers (K=128, NC=128): wave owns 16 cols
    const unsigned short* WLs[3] = {WB1, WB2, WB3};
    const float* bLs[3] = {b1, b2, b3};
    for (int L = 0; L < 3; L++) {
        f32x4 acc[8] = {};
        for (int s = 0; s < 4; s++) {
            {
                short8x va = *reinterpret_cast<const short8x*>(&xT[ar * XT_STRIDE + s * 32 + aq * 8]);
                *reinterpret_cast<short8x*>(&As[swz8(ar, aq)]) = va;
            }
            {
                const unsigned short* wbs = WLs[L] + (size_t)s * 128 * 32;
                int id = tid;                    // 512 threads cover 128x4 chunks
                int c = id >> 2, q = id & 3;
                short8x vb = *reinterpret_cast<const short8x*>(wbs + id * 8);
                *reinterpret_cast<short8x*>(&Bs[swz8(c, q)]) = vb;
            }
            __syncthreads();
            short8x a[8];
            #pragma unroll
            for (int rb = 0; rb < 8; rb++)
                a[rb] = *reinterpret_cast<const short8x*>(&As[swz8(16 * rb + l15, lhi)]);
            int c0 = 16 * wid + l15;
            short8x b = *reinterpret_cast<const short8x*>(&Bs[swz8(c0, lhi)]);
            #pragma unroll
            for (int rb = 0; rb < 8; rb++)
                acc[rb] = __builtin_amdgcn_mfma_f32_16x16x32_bf16(b, a[rb], acc[rb], 0, 0, 0);
            __syncthreads();
        }
        const int cq = 16 * wid + 4 * lhi;
        const float4 bv = *reinterpret_cast<const float4*>(bLs[L] + cq);
        const float bva[4] = {bv.x, bv.y, bv.z, bv.w};
        #pragma unroll
        for (int rb = 0; rb < 8; rb++) {
            int r = 16 * rb + l15;
            ushort4 st;
            unsigned short* o = (unsigned short*)&st;
            #pragma unroll
            for (int j = 0; j < 4; j++)
                o[j] = f2bf_bits(fmaxf(acc[rb][j] + bva[j], 0.f));
            *reinterpret_cast<ushort4*>(&xT[r * XT_STRIDE + cq]) = st;
        }
        __syncthreads();
    }

    // LayerNorm (torch: ddof=1, eps on std); 4 threads/row over 128 rows
    {
        int r = tid >> 2;
        int grp = tid & 3;
        int c0 = grp * 32;
        float xv[32];
        #pragma unroll
        for (int k = 0; k < 4; k++) {
            short8x v = *reinterpret_cast<const short8x*>(&xT[r * XT_STRIDE + c0 + k * 8]);
            #pragma unroll
            for (int j = 0; j < 8; j++) xv[k * 8 + j] = bf_bits2f((unsigned short)v[j]);
        }
        float s = 0.f;
        #pragma unroll
        for (int q = 0; q < 32; q++) s += xv[q];
        s += __shfl_xor(s, 1, 64);
        s += __shfl_xor(s, 2, 64);
        float mean = s * (1.f / 128.f);
        float vs = 0.f;
        #pragma unroll
        for (int q = 0; q < 32; q++) { float d = xv[q] - mean; vs += d * d; }
        vs += __shfl_xor(vs, 1, 64);
        vs += __shfl_xor(vs, 2, 64);
        float inv = 1.f / (sqrtf(vs / 127.f) + 1e-6f);
        int grow = row0 + r;
        #pragma unroll
        for (int k = 0; k < 4; k++) {
            const float4 gm = *reinterpret_cast<const float4*>(gamma + c0 + k * 8);
            const float4 gm2 = *reinterpret_cast<const float4*>(gamma + c0 + k * 8 + 4);
            const float4 bt = *reinterpret_cast<const float4*>(beta + c0 + k * 8);
            const float4 bt2 = *reinterpret_cast<const float4*>(beta + c0 + k * 8 + 4);
            const float gms[8] = {gm.x, gm.y, gm.z, gm.w, gm2.x, gm2.y, gm2.z, gm2.w};
            const float bts[8] = {bt.x, bt.y, bt.z, bt.w, bt2.x, bt2.y, bt2.z, bt2.w};
            float z[8];
            short8x zb;
            #pragma unroll
            for (int j = 0; j < 8; j++) {
                z[j] = gms[j] * (xv[k * 8 + j] - mean) * inv + bts[j];
                zb[j] = (short)f2bf_bits(z[j]);
            }
            *reinterpret_cast<short8x*>(&xT[r * XT_STRIDE + c0 + k * 8]) = zb;
            if (grow < M) {
                float4 z0 = make_float4(z[0], z[1], z[2], z[3]);
                float4 z1 = make_float4(z[4], z[5], z[6], z[7]);
                *reinterpret_cast<float4*>(out_z + (size_t)grow * 128 + c0 + k * 8) = z0;
                *reinterpret_cast<float4*>(out_z + (size_t)grow * 128 + c0 + k * 8 + 4) = z1;
            }
        }
    }
    __syncthreads();

    // UV = z @ WBd (K=128, NC=256): wave owns 32 cols
    {
        f32x4 acc[2][8] = {};
        for (int s = 0; s < 4; s++) {
            {
                short8x va = *reinterpret_cast<const short8x*>(&xT[ar * XT_STRIDE + s * 32 + aq * 8]);
                *reinterpret_cast<short8x*>(&As[swz8(ar, aq)]) = va;
            }
            {
                const unsigned short* wbs = WBd + (size_t)s * 256 * 32;
                #pragma unroll
                for (int i = 0; i < 2; i++) {
                    int id = tid + i * 512;
                    int c = id >> 2, q = id & 3;
                    short8x vb = *reinterpret_cast<const short8x*>(wbs + id * 8);
                    *reinterpret_cast<short8x*>(&Bs[swz8(c, q)]) = vb;
                }
            }
            __syncthreads();
            short8x a[8];
            #pragma unroll
            for (int rb = 0; rb < 8; rb++)
                a[rb] = *reinterpret_cast<const short8x*>(&As[swz8(16 * rb + l15, lhi)]);
            #pragma unroll
            for (int cb = 0; cb < 2; cb++) {
                int c0 = 32 * wid + 16 * cb + l15;
                short8x b = *reinterpret_cast<const short8x*>(&Bs[swz8(c0, lhi)]);
                #pragma unroll
                for (int rb = 0; rb < 8; rb++)
                    acc[cb][rb] = __builtin_amdgcn_mfma_f32_16x16x32_bf16(b, a[rb], acc[cb][rb], 0, 0, 0);
            }
            __syncthreads();
        }
        #pragma unroll
        for (int rb = 0; rb < 8; rb++) {
            int row = row0 + 16 * rb + l15;
            if (row >= M) continue;
            #pragma unroll
            for (int cb = 0; cb < 2; cb++) {
                int cq = 32 * wid + 16 * cb + 4 * lhi;
                ushort4 st;
                st.x = f2bf_bits(acc[cb][rb][0]); st.y = f2bf_bits(acc[cb][rb][1]);
                st.z = f2bf_bits(acc[cb][rb][2]); st.w = f2bf_bits(acc[cb][rb][3]);
                *reinterpret_cast<ushort4*>(UV + (size_t)row * 256 + cq) = st;
            }
        }
    }
}

// ---------------- pair decoder, UV interleaved [M][256] -----------------------
__global__ __launch_bounds__(256) void decoder_pairs(
    const unsigned short* __restrict__ UV,
    const int* __restrict__ xi, const int* __restrict__ yi,
    const float* __restrict__ bd1, const float* __restrict__ Wd2,
    const float* __restrict__ bd2, float* __restrict__ dout, int P)
{
    __shared__ float b1s[128], w2s[128];
    if (threadIdx.x < 128) {
        b1s[threadIdx.x] = bd1[threadIdx.x];
        w2s[threadIdx.x] = Wd2[threadIdx.x];
    }
    __syncthreads();
    int p = blockIdx.x * 256 + threadIdx.x;
    if (p >= P) return;
    const unsigned short* ur = UV + (size_t)xi[p] * 256;
    const unsigned short* vr = UV + (size_t)yi[p] * 256 + 128;
    float part = 0.f;
    #pragma unroll
    for (int j0 = 0; j0 < 128; j0 += 8) {
        const uint4 ua = *reinterpret_cast<const uint4*>(ur + j0);
        const uint4 va = *reinterpret_cast<const uint4*>(vr + j0);
        float uf[8], vf[8];
        uf[0] = bf_bits2f((unsigned short)ua.x); uf[1] = bf_bits2f((unsigned short)(ua.x >> 16));
        uf[2] = bf_bits2f((unsigned short)ua.y); uf[3] = bf_bits2f((unsigned short)(ua.y >> 16));
        uf[4] = bf_bits2f((unsigned short)ua.z); uf[5] = bf_bits2f((unsigned short)(ua.z >> 16));
        uf[6] = bf_bits2f((unsigned short)ua.w); uf[7] = bf_bits2f((unsigned short)(ua.w >> 16));
        vf[0] = bf_bits2f((unsigned short)va.x); vf[1] = bf_bits2f((unsigned short)(va.x >> 16));
        vf[2] = bf_bits2f((unsigned short)va.y); vf[3] = bf_bits2f((unsigned short)(va.y >> 16));
        vf[4] = bf_bits2f((unsigned short)va.z); vf[5] = bf_bits2f((unsigned short)(va.z >> 16));
        vf[6] = bf_bits2f((unsigned short)va.w); vf[7] = bf_bits2f((unsigned short)(va.w >> 16));
        #pragma unroll
        for (int q = 0; q < 8; q++) {
            float t = uf[q] + vf[q] + b1s[j0 + q];
            part += fmaxf(t, 0.f) * w2s[j0 + q];
        }
    }
    dout[p] = sigmoidf_(part + bd2[0]);
}

// ---------------- launcher ----------------------------------------------------
extern "C" void kernel_launch(void* const* d_in, const int* in_sizes, int n_in,
                              void* d_out, int out_size, void* d_ws, size_t ws_size,
                              hipStream_t stream) {
    const float* inputs = (const float*)d_in[0];
    const int* edge_row = (const int*)d_in[1];
    const int* edge_col = (const int*)d_in[2];
    const float* edge_w = (const float*)d_in[3];
    const int* x_idx = (const int*)d_in[4];
    const int* y_idx = (const int*)d_in[5];
    const float* Wr_in = (const float*)d_in[6];  const float* br_in = (const float*)d_in[7];
    const float* Wi_in = (const float*)d_in[8];  const float* bi_in = (const float*)d_in[9];
    const float* Wn_in = (const float*)d_in[10]; const float* bn_in = (const float*)d_in[11];
    const float* Hr_self = (const float*)d_in[12]; const float* Hr_nb = (const float*)d_in[13];
    const float* Hi_self = (const float*)d_in[14]; const float* Hi_nb = (const float*)d_in[15];
    const float* Hh_self = (const float*)d_in[16]; const float* Hh_nb = (const float*)d_in[17];
    const float* W1 = (const float*)d_in[18]; const float* b1 = (const float*)d_in[19];
    const float* W2 = (const float*)d_in[20]; const float* b2 = (const float*)d_in[21];
    const float* W3 = (const float*)d_in[22]; const float* b3 = (const float*)d_in[23];
    const float* gamma = (const float*)d_in[24]; const float* beta = (const float*)d_in[25];
    const float* Wd1 = (const float*)d_in[26]; const float* bd1 = (const float*)d_in[27];
    const float* Wd2 = (const float*)d_in[28]; const float* bd2 = (const float*)d_in[29];

    float* out_d = (float*)d_out;            // [P]
    float* out_z = ((float*)d_out) + NPAIR;  // [N*128]

    // ---- workspace layout (~129 MB) ----
    char* base = (char*)d_ws;
    size_t off = 0;
    auto take = [&](size_t bytes) { void* p = base + off; off = (off + bytes + 255) & ~(size_t)255; return p; };
    int*            row_ptr = (int*)           take((size_t)(N_NODES + 1) * 4);
    unsigned short* WBg     = (unsigned short*)take((size_t)4 * 384 * 64 * 2);   // Hcat 256x384, 64-k chunks
    unsigned short* WBin    = (unsigned short*)take((size_t)8 * 384 * 32 * 2);   // Win 256x384, 32-k chunks
    unsigned short* WB1     = (unsigned short*)take((size_t)4 * 128 * 32 * 2);
    unsigned short* WB2     = (unsigned short*)take((size_t)4 * 128 * 32 * 2);
    unsigned short* WB3     = (unsigned short*)take((size_t)4 * 128 * 32 * 2);
    unsigned short* WBd     = (unsigned short*)take((size_t)4 * 256 * 32 * 2);
    float*          bin     = (float*)         take(384 * 4);
    unsigned short* IN      = (unsigned short*)take((size_t)N_NODES * 384 * 2);  // 76.8 MB; later UV
    unsigned short* hbf     = (unsigned short*)take((size_t)N_NODES * NHID * 2);
    unsigned short* hsbf    = (unsigned short*)take((size_t)N_NODES * NHID * 2);
    if (off > ws_size) return;   // diagnostic marker: d stays 0 -> absmax == 0.586

    // 1. CSR row_ptr
    build_row_ptr<<<(N_NODES + 256) / 256, 256, 0, stream>>>(edge_row, NEDGE, N_NODES, row_ptr);
    // 2. pack all weights in ONE launch (bf16 k-major)
    {
        PackDescs P;
        auto set = [&](int i, const float* src, unsigned short* dst, int K, int NCsrc,
                       int NCtot, int coff, int koff, int kch) {
            P.d[i] = PackDesc{src, dst, K, NCsrc, NCtot, coff, koff, kch};
        };
        set(0,  Hr_self, WBg, 128, 128, 384, 0,   0,   64);
        set(1,  Hi_self, WBg, 128, 128, 384, 128, 0,   64);
        set(2,  Hh_self, WBg, 128, 128, 384, 256, 0,   64);
        set(3,  Hr_nb,   WBg, 128, 128, 384, 0,   128, 64);
        set(4,  Hi_nb,   WBg, 128, 128, 384, 128, 128, 64);
        set(5,  Hh_nb,   WBg, 128, 128, 384, 256, 128, 64);
        set(6,  Wr_in,   WBin, 256, 128, 384, 0,   0, 32);
        set(7,  Wi_in,   WBin, 256, 128, 384, 128, 0, 32);
        set(8,  Wn_in,   WBin, 256, 128, 384, 256, 0, 32);
        set(9,  W1,      WB1, 128, 128, 128, 0, 0, 32);
        set(10, W2,      WB2, 128, 128, 128, 0, 0, 32);
        set(11, W3,      WB3, 128, 128, 128, 0, 0, 32);
        set(12, Wd1,             WBd, 128, 128, 256, 0,   0, 32);
        set(13, Wd1 + 128 * 128, WBd, 128, 128, 256, 128, 0, 32);
        dim3 pg(128, 14);
        pack_all<<<pg, 256, 0, stream>>>(P);
    }
    pack_bin<<<2, 256, 0, stream>>>(br_in, bi_in, bn_in, bin);
    int grid128 = (N_NODES + 127) / 128;
    // 3. IN = inputs @ [Wr|Wi|Wn] + [br|bi|bn]  (one-time, bf16 [N][384])
    in_proj_mfma<<<grid128, 512, 0, stream>>>(inputs, WBin, bin, IN, N_NODES);
    // 4. step 0 (h0 = 0): h1 = (1 - sig(in_i)) * tanh(in_n), pure elementwise
    gru_step0<<<(N_NODES * 16 + 255) / 256, 256, 0, stream>>>(IN, hbf, N_NODES);
    // 5. steps 1..4: spmm -> gate GEMM + GRU (h in place)
    for (int s = 1; s < NSTEPS; s++) {
        spmm_bf16_ilp<<<(N_NODES + 3) / 4, 256, 0, stream>>>(row_ptr, edge_col, edge_w, hbf, hsbf, N_NODES);
        gate_step_mfma<<<grid128, 512, 0, stream>>>(hsbf, hbf, IN, WBg, N_NODES);
    }
    // 6. fused tail: MLP x3 + LayerNorm (z f32 -> d_out) + UV GEMM
    unsigned short* UV = IN;
    mlp_tail<<<grid128, 512, 0, stream>>>(hbf, WB1, WB2, WB3, WBd, b1, b2, b3,
                                          gamma, beta, out_z, UV, N_NODES);
    // 7. pair decoder -> d (f32)
    decoder_pairs<<<(NPAIR + 255) / 256, 256, 0, stream>>>(
        UV, x_idx, y_idx, bd1, Wd2, bd2, out_d, NPAIR);
}

// Round 16
// 944.951 us; speedup vs baseline: 1.0221x; 1.0221x over previous
//
#include <hip/hip_runtime.h>
#include <hip/hip_bf16.h>

#define N_NODES 100000
#define NFEAT 256
#define NHID 128
#define NEDGE 3200000
#define NPAIR 200000
#define NSTEPS 5

typedef __attribute__((ext_vector_type(8))) short short8x;   // 8 bf16 (4 VGPR)
typedef __attribute__((ext_vector_type(4))) float f32x4;

__device__ __forceinline__ float sigmoidf_(float x) {
    return 1.f / (1.f + __expf(-x));
}
__device__ __forceinline__ unsigned short f2bf_bits(float f) {
    union { float f; unsigned int u; } c; c.f = f;
    unsigned int r = (c.u + 0x7FFFu + ((c.u >> 16) & 1u)) >> 16;
    return (unsigned short)r;
}
__device__ __forceinline__ float bf_bits2f(unsigned short b) {
    union { float f; unsigned int u; } c; c.u = ((unsigned int)b) << 16;
    return c.f;
}
// conflict-free LDS chunk offsets
__device__ __forceinline__ int swz8(int row, int q) {     // 32-wide rows
    return row * 32 + ((q + (row >> 1)) & 3) * 8;
}
__device__ __forceinline__ int swz64(int row, int q) {    // 64-wide rows
    return row * 64 + ((q + (row >> 1)) & 7) * 8;
}

// ---------------- utility ------------------------------------------------------
__global__ void build_row_ptr(const int* __restrict__ rows, int E, int N, int* __restrict__ row_ptr) {
    int i = blockIdx.x * blockDim.x + threadIdx.x;
    if (i > N) return;
    int lo = 0, hi = E;
    while (lo < hi) {
        int mid = (lo + hi) >> 1;
        if (rows[mid] < i) lo = mid + 1; else hi = mid;
    }
    row_ptr[i] = lo;
}

// ---------------- mega weight pack (kch = k-chunk size 32 or 64) --------------
struct PackDesc {
    const float* src;
    unsigned short* dst;
    int K, NCsrc, NCtot, coff, koff, kch;
};
struct PackDescs { PackDesc d[14]; };

__global__ void pack_all(PackDescs P) {
    const PackDesc pd = P.d[blockIdx.y];
    int idx = blockIdx.x * 256 + threadIdx.x;
    if (idx >= pd.K * pd.NCsrc) return;
    int k = idx / pd.NCsrc, j = idx - k * pd.NCsrc;
    int kg = k + pd.koff;
    pd.dst[(size_t)(kg / pd.kch) * pd.NCtot * pd.kch + (size_t)(pd.coff + j) * pd.kch + (kg % pd.kch)] =
        f2bf_bits(pd.src[idx]);
}

__global__ void pack_bin(const float* __restrict__ br, const float* __restrict__ bi,
                         const float* __restrict__ bn, float* __restrict__ bin) {
    int i = blockIdx.x * blockDim.x + threadIdx.x;
    if (i >= 384) return;
    bin[i] = (i < 128) ? br[i] : (i < 256) ? bi[i - 128] : bn[i - 256];
}

// ---------------- step 0 specialization: h1 = (1 - sig(in_i)) * tanh(in_n) ----
__global__ __launch_bounds__(256) void gru_step0(
    const unsigned short* __restrict__ IN, unsigned short* __restrict__ hbf, int M)
{
    int t = blockIdx.x * 256 + threadIdx.x;
    int row = t >> 4, ch = (t & 15) * 8;
    if (row >= M) return;
    size_t ib = (size_t)row * 384;
    short8x vi = *reinterpret_cast<const short8x*>(IN + ib + 128 + ch);
    short8x vn = *reinterpret_cast<const short8x*>(IN + ib + 256 + ch);
    short8x o;
    #pragma unroll
    for (int j = 0; j < 8; j++) {
        float ii = sigmoidf_(bf_bits2f((unsigned short)vi[j]));
        float nn = tanhf(bf_bits2f((unsigned short)vn[j]));
        o[j] = (short)f2bf_bits((1.f - ii) * nn);
    }
    *reinterpret_cast<short8x*>(hbf + (size_t)row * 128 + ch) = o;
}

// ---------------- SpMM (bf16), 4 edge streams x 4 unroll ----------------------
#define SPMM_ACC(hv, we) { \
    acc[0] += (we) * bf_bits2f((unsigned short)(hv).x); \
    acc[1] += (we) * bf_bits2f((unsigned short)((hv).x >> 16)); \
    acc[2] += (we) * bf_bits2f((unsigned short)(hv).y); \
    acc[3] += (we) * bf_bits2f((unsigned short)((hv).y >> 16)); \
    acc[4] += (we) * bf_bits2f((unsigned short)(hv).z); \
    acc[5] += (we) * bf_bits2f((unsigned short)((hv).z >> 16)); \
    acc[6] += (we) * bf_bits2f((unsigned short)(hv).w); \
    acc[7] += (we) * bf_bits2f((unsigned short)((hv).w >> 16)); }

__global__ __launch_bounds__(256) void spmm_bf16_ilp(
    const int* __restrict__ row_ptr, const int* __restrict__ col,
    const float* __restrict__ w, const unsigned short* __restrict__ hbf,
    unsigned short* __restrict__ hsbf, int N)
{
    int v = blockIdx.x * 4 + (threadIdx.x >> 6);
    int lane = threadIdx.x & 63;
    int g = lane >> 4;
    int l16 = lane & 15;
    if (v >= N) return;
    int e0 = row_ptr[v], e1 = row_ptr[v + 1];
    float acc[8] = {};
    int e = e0 + g;
    for (; e + 12 < e1; e += 16) {
        int c1 = col[e], c2 = col[e + 4], c3 = col[e + 8], c4 = col[e + 12];
        float w1 = w[e], w2 = w[e + 4], w3 = w[e + 8], w4 = w[e + 12];
        const uint4 h1 = *reinterpret_cast<const uint4*>(hbf + (size_t)c1 * NHID + l16 * 8);
        const uint4 h2 = *reinterpret_cast<const uint4*>(hbf + (size_t)c2 * NHID + l16 * 8);
        const uint4 h3 = *reinterpret_cast<const uint4*>(hbf + (size_t)c3 * NHID + l16 * 8);
        const uint4 h4 = *reinterpret_cast<const uint4*>(hbf + (size_t)c4 * NHID + l16 * 8);
        SPMM_ACC(h1, w1) SPMM_ACC(h2, w2) SPMM_ACC(h3, w3) SPMM_ACC(h4, w4)
    }
    for (; e < e1; e += 4) {
        int cc = col[e];
        float we = w[e];
        const uint4 hv = *reinterpret_cast<const uint4*>(hbf + (size_t)cc * NHID + l16 * 8);
        SPMM_ACC(hv, we)
    }
    #pragma unroll
    for (int q = 0; q < 8; q++) {
        acc[q] += __shfl_xor(acc[q], 16, 64);
        acc[q] += __shfl_xor(acc[q], 32, 64);
    }
    if (g == 0) {
        uint4 o;
        o.x = (unsigned int)f2bf_bits(acc[0]) | ((unsigned int)f2bf_bits(acc[1]) << 16);
        o.y = (unsigned int)f2bf_bits(acc[2]) | ((unsigned int)f2bf_bits(acc[3]) << 16);
        o.z = (unsigned int)f2bf_bits(acc[4]) | ((unsigned int)f2bf_bits(acc[5]) << 16);
        o.w = (unsigned int)f2bf_bits(acc[6]) | ((unsigned int)f2bf_bits(acc[7]) << 16);
        *reinterpret_cast<uint4*>(hsbf + (size_t)v * NHID + l16 * 8) = o;
    }
}

// ---------------- gate GEMM (K=256, BK=64) + GRU: BM=128, 512 threads ---------
// 4 K-phases, two K=32 halves per phase (ascending k -> bit-identical to BK=32).
// WBg packed [s(64k)][384 cols][64 k].
__global__ __launch_bounds__(512, 2) void gate_step_mfma(
    const unsigned short* __restrict__ hsbf, unsigned short* __restrict__ hbf,
    const unsigned short* __restrict__ IN, const unsigned short* __restrict__ WBg, int M)
{
    __shared__ unsigned short As[128 * 64];   // 16 KB
    __shared__ unsigned short Bs[384 * 64];   // 48 KB

    const int tid = threadIdx.x;
    const int wid = tid >> 6;          // 0..7
    const int lane = tid & 63;
    const int row0 = blockIdx.x * 128;
    const int l15 = lane & 15;
    const int lhi = lane >> 4;

    f32x4 acc[3][8] = {};              // [panel][rowblk]

    const int ar = tid >> 2;           // 0..127
    const int aq = tid & 3;            // stages chunks aq and aq+4
    const int agr = row0 + ar;

    for (int s = 0; s < 4; s++) {
        // ---- stage A: 128 rows x 64 k ----
        {
            short8x v0 = short8x(0), v1 = short8x(0);
            if (agr < M) {
                const unsigned short* src = (s < 2)
                    ? (hbf  + (size_t)agr * 128 + s * 64)
                    : (hsbf + (size_t)agr * 128 + (s - 2) * 64);
                v0 = *reinterpret_cast<const short8x*>(src + aq * 8);
                v1 = *reinterpret_cast<const short8x*>(src + (aq + 4) * 8);
            }
            *reinterpret_cast<short8x*>(&As[swz64(ar, aq)]) = v0;
            *reinterpret_cast<short8x*>(&As[swz64(ar, aq + 4)]) = v1;
        }
        // ---- stage B: 384 cols x 64 k ----
        {
            const unsigned short* wbs = WBg + (size_t)s * 384 * 64;
            #pragma unroll
            for (int i = 0; i < 6; i++) {
                int id = tid + i * 512;          // 0..3071
                int c = id >> 3, q = id & 7;
                short8x vb = *reinterpret_cast<const short8x*>(wbs + id * 8);
                *reinterpret_cast<short8x*>(&Bs[swz64(c, q)]) = vb;
            }
        }
        __syncthreads();

        #pragma unroll
        for (int half = 0; half < 2; half++) {
            short8x a[8];
            #pragma unroll
            for (int rb = 0; rb < 8; rb++)
                a[rb] = *reinterpret_cast<const short8x*>(&As[swz64(16 * rb + l15, 4 * half + lhi)]);
            #pragma unroll
            for (int p = 0; p < 3; p++) {
                int c0 = 128 * p + 16 * wid + l15;
                short8x b = *reinterpret_cast<const short8x*>(&Bs[swz64(c0, 4 * half + lhi)]);
                #pragma unroll
                for (int rb = 0; rb < 8; rb++)
                    acc[p][rb] = __builtin_amdgcn_mfma_f32_16x16x32_bf16(b, a[rb], acc[p][rb], 0, 0, 0);
            }
        }
        __syncthreads();
    }

    // GRU epilogue: per lane, row = row0+16rb+l15, 4 consecutive cols at cq
    const int cq = 16 * wid + 4 * lhi;
    #pragma unroll
    for (int rb = 0; rb < 8; rb++) {
        int row = row0 + 16 * rb + l15;
        if (row >= M) continue;
        size_t ib = (size_t)row * 384;
        size_t ob = (size_t)row * 128;
        const ushort4 vr = *reinterpret_cast<const ushort4*>(IN + ib + cq);
        const ushort4 vi = *reinterpret_cast<const ushort4*>(IN + ib + 128 + cq);
        const ushort4 vn = *reinterpret_cast<const ushort4*>(IN + ib + 256 + cq);
        const ushort4 vh = *reinterpret_cast<const ushort4*>(hbf + ob + cq);
        const unsigned short ra[4] = {vr.x, vr.y, vr.z, vr.w};
        const unsigned short ia[4] = {vi.x, vi.y, vi.z, vi.w};
        const unsigned short na[4] = {vn.x, vn.y, vn.z, vn.w};
        const unsigned short ha[4] = {vh.x, vh.y, vh.z, vh.w};
        unsigned short oa[4];
        #pragma unroll
        for (int j = 0; j < 4; j++) {
            float g_r = acc[0][rb][j] + bf_bits2f(ra[j]);
            float g_i = acc[1][rb][j] + bf_bits2f(ia[j]);
            float rr = sigmoidf_(g_r);
            float gi = sigmoidf_(g_i);
            float nn = tanhf(bf_bits2f(na[j]) + rr * acc[2][rb][j]);
            oa[j] = f2bf_bits((1.f - gi) * nn + gi * bf_bits2f(ha[j]));
        }
        ushort4 st; st.x = oa[0]; st.y = oa[1]; st.z = oa[2]; st.w = oa[3];
        *reinterpret_cast<ushort4*>(hbf + ob + cq) = st;
    }
}

// ---------------- IN projection: BM=128, 512 threads, K=256, NC=384 -----------
__global__ __launch_bounds__(512, 2) void in_proj_mfma(
    const float* __restrict__ X, const unsigned short* __restrict__ WBin,
    const float* __restrict__ bin, unsigned short* __restrict__ IN, int M)
{
    __shared__ unsigned short As[128 * 32];   // 8 KB
    __shared__ unsigned short Bs[384 * 32];   // 24 KB

    const int tid = threadIdx.x;
    const int wid = tid >> 6;
    const int lane = tid & 63;
    const int row0 = blockIdx.x * 128;
    const int l15 = lane & 15;
    const int lhi = lane >> 4;

    f32x4 acc[3][8] = {};

    const int ar = tid >> 2;
    const int aq = tid & 3;
    const int agr = row0 + ar;

    for (int s = 0; s < 8; s++) {
        {
            short8x va = short8x(0);
            if (agr < M) {
                const float* src = X + (size_t)agr * 256 + s * 32 + aq * 8;
                const float4 f0 = *reinterpret_cast<const float4*>(src);
                const float4 f1 = *reinterpret_cast<const float4*>(src + 4);
                va[0] = (short)f2bf_bits(f0.x); va[1] = (short)f2bf_bits(f0.y);
                va[2] = (short)f2bf_bits(f0.z); va[3] = (short)f2bf_bits(f0.w);
                va[4] = (short)f2bf_bits(f1.x); va[5] = (short)f2bf_bits(f1.y);
                va[6] = (short)f2bf_bits(f1.z); va[7] = (short)f2bf_bits(f1.w);
            }
            *reinterpret_cast<short8x*>(&As[swz8(ar, aq)]) = va;
        }
        {
            const unsigned short* wbs = WBin + (size_t)s * 384 * 32;
            #pragma unroll
            for (int i = 0; i < 3; i++) {
                int id = tid + i * 512;
                int c = id >> 2, q = id & 3;
                short8x vb = *reinterpret_cast<const short8x*>(wbs + id * 8);
                *reinterpret_cast<short8x*>(&Bs[swz8(c, q)]) = vb;
            }
        }
        __syncthreads();

        short8x a[8];
        #pragma unroll
        for (int rb = 0; rb < 8; rb++)
            a[rb] = *reinterpret_cast<const short8x*>(&As[swz8(16 * rb + l15, lhi)]);
        #pragma unroll
        for (int p = 0; p < 3; p++) {
            int c0 = 128 * p + 16 * wid + l15;
            short8x b = *reinterpret_cast<const short8x*>(&Bs[swz8(c0, lhi)]);
            #pragma unroll
            for (int rb = 0; rb < 8; rb++)
                acc[p][rb] = __builtin_amdgcn_mfma_f32_16x16x32_bf16(b, a[rb], acc[p][rb], 0, 0, 0);
        }
        __syncthreads();
    }

    const int cq = 16 * wid + 4 * lhi;
    float bva[3][4];
    #pragma unroll
    for (int p = 0; p < 3; p++) {
        const float4 bv = *reinterpret_cast<const float4*>(bin + 128 * p + cq);
        bva[p][0] = bv.x; bva[p][1] = bv.y; bva[p][2] = bv.z; bva[p][3] = bv.w;
    }
    #pragma unroll
    for (int rb = 0; rb < 8; rb++) {
        int row = row0 + 16 * rb + l15;
        if (row >= M) continue;
        size_t ib = (size_t)row * 384;
        #pragma unroll
        for (int p = 0; p < 3; p++) {
            ushort4 st;
            st.x = f2bf_bits(acc[p][rb][0] + bva[p][0]);
            st.y = f2bf_bits(acc[p][rb][1] + bva[p][1]);
            st.z = f2bf_bits(acc[p][rb][2] + bva[p][2]);
            st.w = f2bf_bits(acc[p][rb][3] + bva[p][3]);
            *reinterpret_cast<ushort4*>(IN + ib + 128 * p + cq) = st;
        }
    }
}

// ---------------- fused tail: MLP x3 + LayerNorm + UV GEMM (BM=128, 512t) -----
#define XT_STRIDE 136
__global__ __launch_bounds__(512, 2) void mlp_tail(
    const unsigned short* __restrict__ hbf,
    const unsigned short* __restrict__ WB1, const unsigned short* __restrict__ WB2,
    const unsigned short* __restrict__ WB3, const unsigned short* __restrict__ WBd,
    const float* __restrict__ b1, const float* __restrict__ b2, const float* __restrict__ b3,
    const float* __restrict__ gamma, const float* __restrict__ beta,
    float* __restrict__ out_z, unsigned short* __restrict__ UV, int M)
{
    __shared__ unsigned short As[128 * 32];        // 8 KB
    __shared__ unsigned short Bs[256 * 32];        // 16 KB
    __shared__ unsigned short xT[128 * XT_STRIDE]; // 34.8 KB

    const int tid = threadIdx.x;
    const int wid = tid >> 6;        // 0..7
    const int lane = tid & 63;
    const int l15 = lane & 15;
    const int lhi = lane >> 4;
    const int row0 = blockIdx.x * 128;
    const int ar = tid >> 2;         // 0..127
    const int aq = tid & 3;

    // load h tile (128 rows), zero OOB
    #pragma unroll
    for (int i = 0; i < 4; i++) {
        int id = tid + i * 512;          // 0..2047
        int r = id >> 4, ch = id & 15;
        short8x v = short8x(0);
        if (row0 + r < M)
            v = *reinterpret_cast<const short8x*>(hbf + (size_t)(row0 + r) * 128 + ch * 8);
        *reinterpret_cast<short8x*>(&xT[r * XT_STRIDE + ch * 8]) = v;
    }
    __syncthreads();

    // 3 MLP layers (K=128, NC=128): wave owns 16 cols
    const unsigned short* WLs[3] = {WB1, WB2, WB3};
    const float* bLs[3] = {b1, b2, b3};
    for (int L = 0; L < 3; L++) {
        f32x4 acc[8] = {};
        for (int s = 0; s < 4; s++) {
            {
                short8x va = *reinterpret_cast<const short8x*>(&xT[ar * XT_STRIDE + s * 32 + aq * 8]);
                *reinterpret_cast<short8x*>(&As[swz8(ar, aq)]) = va;
            }
            {
                const unsigned short* wbs = WLs[L] + (size_t)s * 128 * 32;
                int id = tid;                    // 512 threads cover 128x4 chunks
                int c = id >> 2, q = id & 3;
                short8x vb = *reinterpret_cast<const short8x*>(wbs + id * 8);
                *reinterpret_cast<short8x*>(&Bs[swz8(c, q)]) = vb;
            }
            __syncthreads();
            short8x a[8];
            #pragma unroll
            for (int rb = 0; rb < 8; rb++)
                a[rb] = *reinterpret_cast<const short8x*>(&As[swz8(16 * rb + l15, lhi)]);
            int c0 = 16 * wid + l15;
            short8x b = *reinterpret_cast<const short8x*>(&Bs[swz8(c0, lhi)]);
            #pragma unroll
            for (int rb = 0; rb < 8; rb++)
                acc[rb] = __builtin_amdgcn_mfma_f32_16x16x32_bf16(b, a[rb], acc[rb], 0, 0, 0);
            __syncthreads();
        }
        const int cq = 16 * wid + 4 * lhi;
        const float4 bv = *reinterpret_cast<const float4*>(bLs[L] + cq);
        const float bva[4] = {bv.x, bv.y, bv.z, bv.w};
        #pragma unroll
        for (int rb = 0; rb < 8; rb++) {
            int r = 16 * rb + l15;
            ushort4 st;
            unsigned short* o = (unsigned short*)&st;
            #pragma unroll
            for (int j = 0; j < 4; j++)
                o[j] = f2bf_bits(fmaxf(acc[rb][j] + bva[j], 0.f));
            *reinterpret_cast<ushort4*>(&xT[r * XT_STRIDE + cq]) = st;
        }
        __syncthreads();
    }

    // LayerNorm (torch: ddof=1, eps on std); 4 threads/row over 128 rows
    {
        int r = tid >> 2;
        int grp = tid & 3;
        int c0 = grp * 32;
        float xv[32];
        #pragma unroll
        for (int k = 0; k < 4; k++) {
            short8x v = *reinterpret_cast<const short8x*>(&xT[r * XT_STRIDE + c0 + k * 8]);
            #pragma unroll
            for (int j = 0; j < 8; j++) xv[k * 8 + j] = bf_bits2f((unsigned short)v[j]);
        }
        float s = 0.f;
        #pragma unroll
        for (int q = 0; q < 32; q++) s += xv[q];
        s += __shfl_xor(s, 1, 64);
        s += __shfl_xor(s, 2, 64);
        float mean = s * (1.f / 128.f);
        float vs = 0.f;
        #pragma unroll
        for (int q = 0; q < 32; q++) { float d = xv[q] - mean; vs += d * d; }
        vs += __shfl_xor(vs, 1, 64);
        vs += __shfl_xor(vs, 2, 64);
        float inv = 1.f / (sqrtf(vs / 127.f) + 1e-6f);
        int grow = row0 + r;
        #pragma unroll
        for (int k = 0; k < 4; k++) {
            const float4 gm = *reinterpret_cast<const float4*>(gamma + c0 + k * 8);
            const float4 gm2 = *reinterpret_cast<const float4*>(gamma + c0 + k * 8 + 4);
            const float4 bt = *reinterpret_cast<const float4*>(beta + c0 + k * 8);
            const float4 bt2 = *reinterpret_cast<const float4*>(beta + c0 + k * 8 + 4);
            const float gms[8] = {gm.x, gm.y, gm.z, gm.w, gm2.x, gm2.y, gm2.z, gm2.w};
            const float bts[8] = {bt.x, bt.y, bt.z, bt.w, bt2.x, bt2.y, bt2.z, bt2.w};
            float z[8];
            short8x zb;
            #pragma unroll
            for (int j = 0; j < 8; j++) {
                z[j] = gms[j] * (xv[k * 8 + j] - mean) * inv + bts[j];
                zb[j] = (short)f2bf_bits(z[j]);
            }
            *reinterpret_cast<short8x*>(&xT[r * XT_STRIDE + c0 + k * 8]) = zb;
            if (grow < M) {
                float4 z0 = make_float4(z[0], z[1], z[2], z[3]);
                float4 z1 = make_float4(z[4], z[5], z[6], z[7]);
                *reinterpret_cast<float4*>(out_z + (size_t)grow * 128 + c0 + k * 8) = z0;
                *reinterpret_cast<float4*>(out_z + (size_t)grow * 128 + c0 + k * 8 + 4) = z1;
            }
        }
    }
    __syncthreads();

    // UV = z @ WBd (K=128, NC=256): wave owns 32 cols
    {
        f32x4 acc[2][8] = {};
        for (int s = 0; s < 4; s++) {
            {
                short8x va = *reinterpret_cast<const short8x*>(&xT[ar * XT_STRIDE + s * 32 + aq * 8]);
                *reinterpret_cast<short8x*>(&As[swz8(ar, aq)]) = va;
            }
            {
                const unsigned short* wbs = WBd + (size_t)s * 256 * 32;
                #pragma unroll
                for (int i = 0; i < 2; i++) {
                    int id = tid + i * 512;
                    int c = id >> 2, q = id & 3;
                    short8x vb = *reinterpret_cast<const short8x*>(wbs + id * 8);
                    *reinterpret_cast<short8x*>(&Bs[swz8(c, q)]) = vb;
                }
            }
            __syncthreads();
            short8x a[8];
            #pragma unroll
            for (int rb = 0; rb < 8; rb++)
                a[rb] = *reinterpret_cast<const short8x*>(&As[swz8(16 * rb + l15, lhi)]);
            #pragma unroll
            for (int cb = 0; cb < 2; cb++) {
                int c0 = 32 * wid + 16 * cb + l15;
                short8x b = *reinterpret_cast<const short8x*>(&Bs[swz8(c0, lhi)]);
                #pragma unroll
                for (int rb = 0; rb < 8; rb++)
                    acc[cb][rb] = __builtin_amdgcn_mfma_f32_16x16x32_bf16(b, a[rb], acc[cb][rb], 0, 0, 0);
            }
            __syncthreads();
        }
        #pragma unroll
        for (int rb = 0; rb < 8; rb++) {
            int row = row0 + 16 * rb + l15;
            if (row >= M) continue;
            #pragma unroll
            for (int cb = 0; cb < 2; cb++) {
                int cq = 32 * wid + 16 * cb + 4 * lhi;
                ushort4 st;
                st.x = f2bf_bits(acc[cb][rb][0]); st.y = f2bf_bits(acc[cb][rb][1]);
                st.z = f2bf_bits(acc[cb][rb][2]); st.w = f2bf_bits(acc[cb][rb][3]);
                *reinterpret_cast<ushort4*>(UV + (size_t)row * 256 + cq) = st;
            }
        }
    }
}

// ---------------- pair decoder, UV interleaved [M][256] -----------------------
__global__ __launch_bounds__(256) void decoder_pairs(
    const unsigned short* __restrict__ UV,
    const int* __restrict__ xi, const int* __restrict__ yi,
    const float* __restrict__ bd1, const float* __restrict__ Wd2,
    const float* __restrict__ bd2, float* __restrict__ dout, int P)
{
    __shared__ float b1s[128], w2s[128];
    if (threadIdx.x < 128) {
        b1s[threadIdx.x] = bd1[threadIdx.x];
        w2s[threadIdx.x] = Wd2[threadIdx.x];
    }
    __syncthreads();
    int p = blockIdx.x * 256 + threadIdx.x;
    if (p >= P) return;
    const unsigned short* ur = UV + (size_t)xi[p] * 256;
    const unsigned short* vr = UV + (size_t)yi[p] * 256 + 128;
    float part = 0.f;
    #pragma unroll
    for (int j0 = 0; j0 < 128; j0 += 8) {
        const uint4 ua = *reinterpret_cast<const uint4*>(ur + j0);
        const uint4 va = *reinterpret_cast<const uint4*>(vr + j0);
        float uf[8], vf[8];
        uf[0] = bf_bits2f((unsigned short)ua.x); uf[1] = bf_bits2f((unsigned short)(ua.x >> 16));
        uf[2] = bf_bits2f((unsigned short)ua.y); uf[3] = bf_bits2f((unsigned short)(ua.y >> 16));
        uf[4] = bf_bits2f((unsigned short)ua.z); uf[5] = bf_bits2f((unsigned short)(ua.z >> 16));
        uf[6] = bf_bits2f((unsigned short)ua.w); uf[7] = bf_bits2f((unsigned short)(ua.w >> 16));
        vf[0] = bf_bits2f((unsigned short)va.x); vf[1] = bf_bits2f((unsigned short)(va.x >> 16));
        vf[2] = bf_bits2f((unsigned short)va.y); vf[3] = bf_bits2f((unsigned short)(va.y >> 16));
        vf[4] = bf_bits2f((unsigned short)va.z); vf[5] = bf_bits2f((unsigned short)(va.z >> 16));
        vf[6] = bf_bits2f((unsigned short)va.w); vf[7] = bf_bits2f((unsigned short)(va.w >> 16));
        #pragma unroll
        for (int q = 0; q < 8; q++) {
            float t = uf[q] + vf[q] + b1s[j0 + q];
            part += fmaxf(t, 0.f) * w2s[j0 + q];
        }
    }
    dout[p] = sigmoidf_(part + bd2[0]);
}

// ---------------- launcher ----------------------------------------------------
extern "C" void kernel_launch(void* const* d_in, const int* in_sizes, int n_in,
                              void* d_out, int out_size, void* d_ws, size_t ws_size,
                              hipStream_t stream) {
    const float* inputs = (const float*)d_in[0];
    const int* edge_row = (const int*)d_in[1];
    const int* edge_col = (const int*)d_in[2];
    const float* edge_w = (const float*)d_in[3];
    const int* x_idx = (const int*)d_in[4];
    const int* y_idx = (const int*)d_in[5];
    const float* Wr_in = (const float*)d_in[6];  const float* br_in = (const float*)d_in[7];
    const float* Wi_in = (const float*)d_in[8];  const float* bi_in = (const float*)d_in[9];
    const float* Wn_in = (const float*)d_in[10]; const float* bn_in = (const float*)d_in[11];
    const float* Hr_self = (const float*)d_in[12]; const float* Hr_nb = (const float*)d_in[13];
    const float* Hi_self = (const float*)d_in[14]; const float* Hi_nb = (const float*)d_in[15];
    const float* Hh_self = (const float*)d_in[16]; const float* Hh_nb = (const float*)d_in[17];
    const float* W1 = (const float*)d_in[18]; const float* b1 = (const float*)d_in[19];
    const float* W2 = (const float*)d_in[20]; const float* b2 = (const float*)d_in[21];
    const float* W3 = (const float*)d_in[22]; const float* b3 = (const float*)d_in[23];
    const float* gamma = (const float*)d_in[24]; const float* beta = (const float*)d_in[25];
    const float* Wd1 = (const float*)d_in[26]; const float* bd1 = (const float*)d_in[27];
    const float* Wd2 = (const float*)d_in[28]; const float* bd2 = (const float*)d_in[29];

    float* out_d = (float*)d_out;            // [P]
    float* out_z = ((float*)d_out) + NPAIR;  // [N*128]

    // ---- workspace layout (~129 MB) ----
    char* base = (char*)d_ws;
    size_t off = 0;
    auto take = [&](size_t bytes) { void* p = base + off; off = (off + bytes + 255) & ~(size_t)255; return p; };
    int*            row_ptr = (int*)           take((size_t)(N_NODES + 1) * 4);
    unsigned short* WBg     = (unsigned short*)take((size_t)4 * 384 * 64 * 2);   // Hcat 256x384, 64-k chunks
    unsigned short* WBin    = (unsigned short*)take((size_t)8 * 384 * 32 * 2);   // Win 256x384, 32-k chunks
    unsigned short* WB1     = (unsigned short*)take((size_t)4 * 128 * 32 * 2);
    unsigned short* WB2     = (unsigned short*)take((size_t)4 * 128 * 32 * 2);
    unsigned short* WB3     = (unsigned short*)take((size_t)4 * 128 * 32 * 2);
    unsigned short* WBd     = (unsigned short*)take((size_t)4 * 256 * 32 * 2);
    float*          bin     = (float*)         take(384 * 4);
    unsigned short* IN      = (unsigned short*)take((size_t)N_NODES * 384 * 2);  // 76.8 MB; later UV
    unsigned short* hbf     = (unsigned short*)take((size_t)N_NODES * NHID * 2);
    unsigned short* hsbf    = (unsigned short*)take((size_t)N_NODES * NHID * 2);
    if (off > ws_size) return;   // diagnostic marker: d stays 0 -> absmax == 0.586

    // 1. CSR row_ptr
    build_row_ptr<<<(N_NODES + 256) / 256, 256, 0, stream>>>(edge_row, NEDGE, N_NODES, row_ptr);
    // 2. pack all weights in ONE launch (bf16 k-major)
    {
        PackDescs P;
        auto set = [&](int i, const float* src, unsigned short* dst, int K, int NCsrc,
                       int NCtot, int coff, int koff, int kch) {
            P.d[i] = PackDesc{src, dst, K, NCsrc, NCtot, coff, koff, kch};
        };
        set(0,  Hr_self, WBg, 128, 128, 384, 0,   0,   64);
        set(1,  Hi_self, WBg, 128, 128, 384, 128, 0,   64);
        set(2,  Hh_self, WBg, 128, 128, 384, 256, 0,   64);
        set(3,  Hr_nb,   WBg, 128, 128, 384, 0,   128, 64);
        set(4,  Hi_nb,   WBg, 128, 128, 384, 128, 128, 64);
        set(5,  Hh_nb,   WBg, 128, 128, 384, 256, 128, 64);
        set(6,  Wr_in,   WBin, 256, 128, 384, 0,   0, 32);
        set(7,  Wi_in,   WBin, 256, 128, 384, 128, 0, 32);
        set(8,  Wn_in,   WBin, 256, 128, 384, 256, 0, 32);
        set(9,  W1,      WB1, 128, 128, 128, 0, 0, 32);
        set(10, W2,      WB2, 128, 128, 128, 0, 0, 32);
        set(11, W3,      WB3, 128, 128, 128, 0, 0, 32);
        set(12, Wd1,             WBd, 128, 128, 256, 0,   0, 32);
        set(13, Wd1 + 128 * 128, WBd, 128, 128, 256, 128, 0, 32);
        dim3 pg(128, 14);
        pack_all<<<pg, 256, 0, stream>>>(P);
    }
    pack_bin<<<2, 256, 0, stream>>>(br_in, bi_in, bn_in, bin);
    int grid128 = (N_NODES + 127) / 128;
    // 3. IN = inputs @ [Wr|Wi|Wn] + [br|bi|bn]  (one-time, bf16 [N][384])
    in_proj_mfma<<<grid128, 512, 0, stream>>>(inputs, WBin, bin, IN, N_NODES);
    // 4. step 0 (h0 = 0): h1 = (1 - sig(in_i)) * tanh(in_n), pure elementwise
    gru_step0<<<(N_NODES * 16 + 255) / 256, 256, 0, stream>>>(IN, hbf, N_NODES);
    // 5. steps 1..4: spmm -> gate GEMM + GRU (h in place)
    for (int s = 1; s < NSTEPS; s++) {
        spmm_bf16_ilp<<<(N_NODES + 3) / 4, 256, 0, stream>>>(row_ptr, edge_col, edge_w, hbf, hsbf, N_NODES);
        gate_step_mfma<<<grid128, 512, 0, stream>>>(hsbf, hbf, IN, WBg, N_NODES);
    }
    // 6. fused tail: MLP x3 + LayerNorm (z f32 -> d_out) + UV GEMM
    unsigned short* UV = IN;
    mlp_tail<<<grid128, 512, 0, stream>>>(hbf, WB1, WB2, WB3, WBd, b1, b2, b3,
                                          gamma, beta, out_z, UV, N_NODES);
    // 7. pair decoder -> d (f32)
    decoder_pairs<<<(NPAIR + 255) / 256, 256, 0, stream>>>(
        UV, x_idx, y_idx, bd1, Wd2, bd2, out_d, NPAIR);
}